// Round 3
// baseline (683.435 us; speedup 1.0000x reference)
//
#include <hip/hip_runtime.h>

#define S 128
#define L (S*S)
#define AK 21
#define AC 2
#define PP 882          // AC*AK*AK
#define HX 148          // S + AK - 1
#define LK 41
#define KK 1681         // LK*LK
#define EX 9
#define MAXR 19
#define NITER 5
#define NW 16           // waves per block in transposed latneg

// ---------- helpers ----------

__device__ __forceinline__ int reflect_idx(int i) {
  i = (i < 0) ? -i : i;
  return (i >= S) ? (2 * S - 2 - i) : i;
}

__device__ __forceinline__ void wave_red2(float& a, float& b) {
#pragma unroll
  for (int o = 32; o; o >>= 1) {
    a += __shfl_down(a, o);
    b += __shfl_down(b, o);
  }
}

__device__ __forceinline__ float gmap(const float* __restrict__ m,
                                      int i, int j, int kh, int kw) {
  int ii = i + kh - LK / 2;
  int jj = j + kw - LK / 2;
  return ((unsigned)ii < (unsigned)S && (unsigned)jj < (unsigned)S)
             ? m[ii * S + jj] : 0.f;
}

// ---------- transpose: lw [L][KK] -> lwT [KK][L], plus row sums wsum[L] ----------
__global__ void k_transpose(const float* __restrict__ lw,
                            float* __restrict__ lwT,
                            float* __restrict__ wsum) {
  __shared__ float tile[64][65];
  int kt = blockIdx.x;            // 0..26
  int lt = blockIdx.y;            // 0..255
  int tid = threadIdx.x;          // 256
  int c = tid & 63, r0 = tid >> 6;
#pragma unroll
  for (int p = 0; p < 16; ++p) {
    int r = r0 + (p << 2);
    int k = kt * 64 + c;
    int l = lt * 64 + r;
    tile[r][c] = (k < KK) ? lw[(size_t)l * KK + k] : 0.f;
  }
  __syncthreads();
  if (tid < 64) {
    float s = 0.f;
    for (int cc = 0; cc < 64; ++cc) s += tile[tid][cc];
    atomicAdd(&wsum[lt * 64 + tid], s);
  }
#pragma unroll
  for (int p = 0; p < 16; ++p) {
    int rr = r0 + (p << 2);       // tile-local k
    int k = kt * 64 + rr;
    if (k < KK) lwT[(size_t)k * L + lt * 64 + c] = tile[c][rr];
  }
}

// ---------- K1: x_tiles + raw_aff + aff + initial lat + zero mean ----------
__global__ void k_xtiles(const float* __restrict__ x,
                         const float* __restrict__ rfs,
                         const float* __restrict__ adath,
                         const float* __restrict__ aenv,
                         float* __restrict__ out_raw,
                         float* __restrict__ out_xt,
                         float* __restrict__ aff,
                         float* __restrict__ latA,
                         float* __restrict__ mean) {
  int wid = (blockIdx.x * blockDim.x + threadIdx.x) >> 6;
  int lane = threadIdx.x & 63;
  if (wid >= L) return;
  int i = wid >> 7, j = wid & (S - 1);
  const float2* rrow2 = (const float2*)(rfs + (size_t)wid * PP);
  float2* xrow2 = (float2*)(out_xt + (size_t)wid * PP);
  const float2* aenv2 = (const float2*)aenv;
  float accd = 0.f, accs = 0.f;
  for (int q = lane; q < PP / 2; q += 64) {
    float2 w2 = rrow2[q];
    float2 e2 = aenv2[q];
    int p0 = q << 1;
    int c = (p0 >= 441) ? 1 : 0;
    int r = p0 - c * 441;
    int kh = r / AK, kw = r - kh * AK;
    float xt0 = x[c * (HX * HX) + (i + kh) * HX + (j + kw)] * e2.x;
    int p1 = p0 + 1;
    int c1 = (p1 >= 441) ? 1 : 0;
    int r1 = p1 - c1 * 441;
    int kh1 = r1 / AK, kw1 = r1 - kh1 * AK;
    float xt1 = x[c1 * (HX * HX) + (i + kh1) * HX + (j + kw1)] * e2.y;
    xrow2[q] = make_float2(xt0, xt1);
    accd += xt0 * w2.x + xt1 * w2.y;
    accs += w2.x + w2.y;
  }
  wave_red2(accd, accs);
  if (lane == 0) {
    out_raw[wid] = accd * ((float)PP / accs);
    float a = accd / accs - adath[wid];
    aff[wid] = a;
    latA[wid] = a > 0.f ? a : 0.f;
    mean[wid] = 0.f;
  }
}

// ---------- K2: 9x9 reflect-pad convolution (wave per pixel) ----------
__global__ void k_conv(const float* __restrict__ latA,
                       const float* __restrict__ sre,
                       float* __restrict__ latC) {
  int wid = (blockIdx.x * blockDim.x + threadIdx.x) >> 6;
  int lane = threadIdx.x & 63;
  if (wid >= L) return;
  int i = wid >> 7, j = wid & (S - 1);
  float acc = 0.f;
#pragma unroll
  for (int t0 = 0; t0 < 2; ++t0) {
    int t = t0 * 64 + lane;
    if (t < EX * EX) {
      int u = t / EX, v = t - u * EX;
      int ii = reflect_idx(i + u - EX / 2);
      int jj = reflect_idx(j + v - EX / 2);
      acc += latA[ii * S + jj] * sre[t];
    }
  }
#pragma unroll
  for (int o = 32; o; o >>= 1) acc += __shfl_xor(acc, o);
  if (lane == 0) latC[wid] = acc;
}

// ---------- K3 (transposed): lat_neg + update ----------
// block = 1024 threads (16 waves) per 64-pixel group; lane <-> pixel;
// wave w handles k = w, w+16, ... (balanced); skip env==0 / OOB rows entirely.
__global__ __launch_bounds__(1024)
void k_latneg_t(const float* __restrict__ lwT,
                const float* __restrict__ wsum,
                const float* __restrict__ envk,
                const float* __restrict__ latC,
                const float* __restrict__ aff,
                float* __restrict__ lat2) {
  int b = blockIdx.x;             // 0..255
  int tid = threadIdx.x;
  int wave = tid >> 6, lane = tid & 63;
  int l0 = b << 6;
  int i = l0 >> 7;                // uniform row for the whole block
  int jb = (b & 1) << 6;          // 0 or 64
  float acc = 0.f;
  for (int k = wave; k < KK; k += NW) {
    float ek = envk[k];
    if (ek == 0.f) continue;
    int kh = k / LK, kw = k - kh * LK;
    int ii = i + kh - LK / 2;
    if ((unsigned)ii >= (unsigned)S) continue;
    int jj = jb + kw - LK / 2 + lane;
    float pv = ((unsigned)jj < (unsigned)S) ? latC[ii * S + jj] : 0.f;
    acc += lwT[(size_t)k * L + l0 + lane] * ek * pv;
  }
  __shared__ float red[NW][64];
  red[wave][lane] = acc;
  __syncthreads();
  if (wave == 0) {
    float s = 0.f;
#pragma unroll
    for (int w = 0; w < NW; ++w) s += red[w][lane];
    int l = l0 + lane;
    float ln = s / wsum[l];
    float v = latC[l] - ln + aff[l];
    lat2[l] = (v > 0.f ? v : 0.f) * 1.5f;
  }
}

// ---------- K4: 19x19 masked max + normalize + mean accum (wave per pixel) ----------
__global__ void k_maxnorm(const float* __restrict__ lat2,
                          const float* __restrict__ mmask,
                          float* __restrict__ latA,
                          float* __restrict__ mean,
                          float* __restrict__ out_lat,
                          int last) {
  int wid = (blockIdx.x * blockDim.x + threadIdx.x) >> 6;
  int lane = threadIdx.x & 63;
  if (wid >= L) return;
  int i = wid >> 7, j = wid & (S - 1);
  float m = 1.0f;
#pragma unroll
  for (int t0 = 0; t0 < 6; ++t0) {
    int t = t0 * 64 + lane;
    if (t < MAXR * MAXR) {
      int u = t / MAXR, v = t - u * MAXR;
      int ii = reflect_idx(i + u - MAXR / 2);
      int jj = reflect_idx(j + v - MAXR / 2);
      m = fmaxf(m, lat2[ii * S + jj] * mmask[t]);
    }
  }
#pragma unroll
  for (int o = 32; o; o >>= 1) m = fmaxf(m, __shfl_xor(m, o));
  if (lane == 0) {
    float lv = lat2[wid] / (m + 1e-5f);
    latA[wid] = lv;
    mean[wid] += lv;
    if (last) out_lat[wid] = lv;
  }
}

// ---------- K5 (transposed): correlation, atomicAdd per block ----------
__global__ __launch_bounds__(1024)
void k_corr_t(const float* __restrict__ lwT,
              const float* __restrict__ wsum,
              const float* __restrict__ envk,
              const float* __restrict__ mean,
              float* __restrict__ out_cor) {
  int b = blockIdx.x;
  int tid = threadIdx.x;
  int wave = tid >> 6, lane = tid & 63;
  int l0 = b << 6;
  int i = l0 >> 7;
  int jb = (b & 1) << 6;
  float acc = 0.f;
  for (int k = wave; k < KK; k += NW) {
    float ek = envk[k];
    if (ek == 0.f) continue;
    int kh = k / LK, kw = k - kh * LK;
    int ii = i + kh - LK / 2;
    if ((unsigned)ii >= (unsigned)S) continue;
    int jj = jb + kw - LK / 2 + lane;
    float pv = ((unsigned)jj < (unsigned)S) ? mean[ii * S + jj] : 0.f;
    acc += lwT[(size_t)k * L + l0 + lane] * ek * pv;
  }
  __shared__ float red[NW][64];
  red[wave][lane] = acc;
  __syncthreads();
  if (wave == 0) {
    float s = 0.f;
#pragma unroll
    for (int w = 0; w < NW; ++w) s += red[w][lane];
    int l = l0 + lane;
    const float inv_it = 1.0f / (float)NITER;
    float lm = mean[l] * inv_it;
    float c = lm * ((float)KK / wsum[l]) * (s * inv_it);
#pragma unroll
    for (int o = 32; o; o >>= 1) c += __shfl_down(c, o);
    if (lane == 0) atomicAdd(out_cor, c);
  }
}

// ================= fallback path (round-2 kernels, no transpose) =================

__device__ __forceinline__ void row_scan(const float* __restrict__ lw,
                                         const float* __restrict__ envk,
                                         const float* __restrict__ m,
                                         int wid, int lane,
                                         float& accn, float& accw) {
  int i = wid >> 7, j = wid & (S - 1);
  const float* wrow = lw + (size_t)wid * KK;
  const int pro = (4 - (wid & 3)) & 3;
  const int n4 = (KK - pro) >> 2;
  const int tail = (KK - pro) & 3;
  accn = 0.f; accw = 0.f;
  if (lane < pro) {
    int k = lane;
    float w = wrow[k];
    int kh = k / LK, kw = k - kh * LK;
    accw += w;
    accn += w * envk[k] * gmap(m, i, j, kh, kw);
  }
  const float4* wrow4 = (const float4*)(wrow + pro);
  for (int q = lane; q < n4; q += 64) {
    float4 w4 = wrow4[q];
    int k0 = pro + (q << 2);
    int kh = k0 / LK;
    int kw = k0 - kh * LK;
    accw += (w4.x + w4.y) + (w4.z + w4.w);
    float a;
    a = w4.x * envk[k0]     * gmap(m, i, j, kh, kw);
    kw++; if (kw >= LK) { kw -= LK; kh++; }
    a += w4.y * envk[k0 + 1] * gmap(m, i, j, kh, kw);
    kw++; if (kw >= LK) { kw -= LK; kh++; }
    a += w4.z * envk[k0 + 2] * gmap(m, i, j, kh, kw);
    kw++; if (kw >= LK) { kw -= LK; kh++; }
    a += w4.w * envk[k0 + 3] * gmap(m, i, j, kh, kw);
    accn += a;
  }
  if (lane < tail) {
    int k = pro + (n4 << 2) + lane;
    float w = wrow[k];
    int kh = k / LK, kw = k - kh * LK;
    accw += w;
    accn += w * envk[k] * gmap(m, i, j, kh, kw);
  }
  wave_red2(accn, accw);
}

__global__ void k_latneg(const float* __restrict__ lw,
                         const float* __restrict__ envk,
                         const float* __restrict__ latC,
                         const float* __restrict__ aff,
                         float* __restrict__ lat2) {
  int wid = (blockIdx.x * blockDim.x + threadIdx.x) >> 6;
  int lane = threadIdx.x & 63;
  if (wid >= L) return;
  float accn, accw;
  row_scan(lw, envk, latC, wid, lane, accn, accw);
  if (lane == 0) {
    float ln = accn / accw;
    float v = latC[wid] - ln + aff[wid];
    lat2[wid] = (v > 0.f ? v : 0.f) * 1.5f;
  }
}

__global__ void k_corrpart(const float* __restrict__ lw,
                           const float* __restrict__ envk,
                           const float* __restrict__ mean,
                           float* __restrict__ part) {
  int wid = (blockIdx.x * blockDim.x + threadIdx.x) >> 6;
  int lane = threadIdx.x & 63;
  if (wid >= L) return;
  float accn, accw;
  row_scan(lw, envk, mean, wid, lane, accn, accw);
  if (lane == 0) {
    const float inv_it = 1.0f / (float)NITER;
    float lm = mean[wid] * inv_it;
    part[wid] = lm * ((float)KK / accw) * (accn * inv_it);
  }
}

__global__ void k_reduce(const float* __restrict__ part,
                         float* __restrict__ out) {
  float a = 0.f;
  for (int idx = threadIdx.x; idx < L; idx += 256) a += part[idx];
#pragma unroll
  for (int o = 32; o; o >>= 1) a += __shfl_down(a, o);
  __shared__ float sm[4];
  if ((threadIdx.x & 63) == 0) sm[threadIdx.x >> 6] = a;
  __syncthreads();
  if (threadIdx.x == 0) out[0] = sm[0] + sm[1] + sm[2] + sm[3];
}

// ---------- launch ----------
extern "C" void kernel_launch(void* const* d_in, const int* in_sizes, int n_in,
                              void* d_out, int out_size, void* d_ws, size_t ws_size,
                              hipStream_t stream) {
  const float* x     = (const float*)d_in[0];
  const float* rfs   = (const float*)d_in[1];
  const float* lw    = (const float*)d_in[2];
  const float* adath = (const float*)d_in[3];
  const float* aenv  = (const float*)d_in[4];
  const float* sre   = (const float*)d_in[5];
  const float* envk  = (const float*)d_in[6];
  const float* mmask = (const float*)d_in[7];

  float* out = (float*)d_out;
  float* out_raw = out;             // 16384
  float* out_lat = out + L;         // 16384
  float* out_cor = out + 2 * L;     // 1
  float* out_xt  = out + 2 * L + 1; // 16384*882

  dim3 blk(256);
  dim3 grid_wave(L / 4);            // wave-per-pixel kernels

  size_t need = ((size_t)KK * L + 8 * (size_t)L) * sizeof(float);

  if (ws_size >= need) {
    float* wsf  = (float*)d_ws;
    float* lwT  = wsf;                         // KK*L
    float* wsum = wsf + (size_t)KK * L;        // L
    float* aff  = wsum + L;
    float* latA = aff + L;
    float* latC = latA + L;
    float* lat2 = latC + L;
    float* mean = lat2 + L;

    hipMemsetAsync(wsum, 0, L * sizeof(float), stream);
    hipMemsetAsync(out_cor, 0, sizeof(float), stream);

    k_transpose<<<dim3(27, 256), blk, 0, stream>>>(lw, lwT, wsum);
    k_xtiles<<<grid_wave, blk, 0, stream>>>(x, rfs, adath, aenv,
                                            out_raw, out_xt, aff, latA, mean);
    for (int it = 0; it < NITER; ++it) {
      k_conv<<<grid_wave, blk, 0, stream>>>(latA, sre, latC);
      k_latneg_t<<<dim3(L / 64), dim3(64 * NW), 0, stream>>>(lwT, wsum, envk,
                                                             latC, aff, lat2);
      k_maxnorm<<<grid_wave, blk, 0, stream>>>(lat2, mmask, latA, mean, out_lat,
                                               (it == NITER - 1) ? 1 : 0);
    }
    k_corr_t<<<dim3(L / 64), dim3(64 * NW), 0, stream>>>(lwT, wsum, envk,
                                                         mean, out_cor);
  } else {
    float* wsf  = (float*)d_ws;
    float* aff  = wsf;
    float* latA = wsf + L;
    float* latC = wsf + 2 * L;
    float* lat2 = wsf + 3 * L;
    float* mean = wsf + 4 * L;
    float* part = wsf + 5 * L;

    k_xtiles<<<grid_wave, blk, 0, stream>>>(x, rfs, adath, aenv,
                                            out_raw, out_xt, aff, latA, mean);
    for (int it = 0; it < NITER; ++it) {
      k_conv<<<grid_wave, blk, 0, stream>>>(latA, sre, latC);
      k_latneg<<<grid_wave, blk, 0, stream>>>(lw, envk, latC, aff, lat2);
      k_maxnorm<<<grid_wave, blk, 0, stream>>>(lat2, mmask, latA, mean, out_lat,
                                               (it == NITER - 1) ? 1 : 0);
    }
    k_corrpart<<<grid_wave, blk, 0, stream>>>(lw, envk, mean, part);
    k_reduce<<<1, blk, 0, stream>>>(part, out_cor);
  }
}

// Round 5
// 473.323 us; speedup vs baseline: 1.4439x; 1.4439x over previous
//
#include <hip/hip_runtime.h>

#define S 128
#define L (S*S)
#define AK 21
#define AC 2
#define PP 882          // AC*AK*AK
#define HX 148          // S + AK - 1
#define LK 41
#define KK 1681         // LK*LK
#define EX 9
#define MAXR 19
#define NITER 5
#define PSTR 168        // padded map stride (rows/cols: [-20,147] + 20)
#define MAPSZ (PSTR*PSTR)
#define KLMAX 1684

// ---------- helpers ----------

__device__ __forceinline__ int reflect_idx(int i) {
  i = (i < 0) ? -i : i;
  return (i >= S) ? (2 * S - 2 - i) : i;
}

__device__ __forceinline__ void wave_red2(float& a, float& b) {
#pragma unroll
  for (int o = 32; o; o >>= 1) {
    a += __shfl_down(a, o);
    b += __shfl_down(b, o);
  }
}

// ---------- klist: compact {k*L, (kh-20)*PSTR + (kw-20)} for envk[k] != 0 ----------
__global__ void k_klist(const float* __restrict__ envk,
                        int2* __restrict__ klist,
                        int* __restrict__ nact) {
  int lane = threadIdx.x;          // 64 threads
  int base = 0;
  for (int c = 0; c < (KK + 63) / 64; ++c) {
    int k = c * 64 + lane;
    bool pred = (k < KK) && (envk[k] != 0.f);
    unsigned long long mask = __ballot(pred);
    int pos = base + (int)__popcll(mask & ((1ull << lane) - 1ull));
    if (pred) {
      int kh = k / LK, kw = k - kh * LK;
      klist[pos] = make_int2(k * L, (kh - LK / 2) * PSTR + (kw - LK / 2));
    }
    base += (int)__popcll(mask);
  }
  if (lane == 0) *nact = base;
}

// ---------- transpose: lw [L][KK] -> lwT [KK][L] with envk folded, + wsum ----------
__global__ void k_transpose(const float* __restrict__ lw,
                            const float* __restrict__ envk,
                            float* __restrict__ lwT,
                            float* __restrict__ wsum) {
  __shared__ float tile[64][65];
  int kt = blockIdx.x;            // 0..26
  int lt = blockIdx.y;            // 0..255
  int tid = threadIdx.x;          // 256
  int c = tid & 63, r0 = tid >> 6;
#pragma unroll
  for (int p = 0; p < 16; ++p) {
    int r = r0 + (p << 2);
    int k = kt * 64 + c;
    int l = lt * 64 + r;
    tile[r][c] = (k < KK) ? lw[(size_t)l * KK + k] : 0.f;
  }
  __syncthreads();
  if (tid < 64) {
    float s = 0.f;
    for (int cc = 0; cc < 64; ++cc) s += tile[tid][cc];
    atomicAdd(&wsum[lt * 64 + tid], s);
  }
#pragma unroll
  for (int p = 0; p < 16; ++p) {
    int rr = r0 + (p << 2);       // tile-local k
    int k = kt * 64 + rr;
    if (k < KK) {
      float e = envk[k];
      if (e != 0.f)
        lwT[(size_t)k * L + lt * 64 + c] = tile[c][rr] * e;
    }
  }
}

// ---------- K1: x_tiles + raw_aff + aff + initial lat ----------
__global__ void k_xtiles(const float* __restrict__ x,
                         const float* __restrict__ rfs,
                         const float* __restrict__ adath,
                         const float* __restrict__ aenv,
                         float* __restrict__ out_raw,
                         float* __restrict__ out_xt,
                         float* __restrict__ aff,
                         float* __restrict__ latA) {
  int wid = (blockIdx.x * blockDim.x + threadIdx.x) >> 6;
  int lane = threadIdx.x & 63;
  if (wid >= L) return;
  int i = wid >> 7, j = wid & (S - 1);
  const float2* rrow2 = (const float2*)(rfs + (size_t)wid * PP);
  float2* xrow2 = (float2*)(out_xt + (size_t)wid * PP);
  const float2* aenv2 = (const float2*)aenv;
  float accd = 0.f, accs = 0.f;
  for (int q = lane; q < PP / 2; q += 64) {
    float2 w2 = rrow2[q];
    float2 e2 = aenv2[q];
    int p0 = q << 1;
    int c = (p0 >= 441) ? 1 : 0;
    int r = p0 - c * 441;
    int kh = r / AK, kw = r - kh * AK;
    float xt0 = x[c * (HX * HX) + (i + kh) * HX + (j + kw)] * e2.x;
    int p1 = p0 + 1;
    int c1 = (p1 >= 441) ? 1 : 0;
    int r1 = p1 - c1 * 441;
    int kh1 = r1 / AK, kw1 = r1 - kh1 * AK;
    float xt1 = x[c1 * (HX * HX) + (i + kh1) * HX + (j + kw1)] * e2.y;
    xrow2[q] = make_float2(xt0, xt1);
    accd += xt0 * w2.x + xt1 * w2.y;
    accs += w2.x + w2.y;
  }
  wave_red2(accd, accs);
  if (lane == 0) {
    out_raw[wid] = accd * ((float)PP / accs);
    float a = accd / accs - adath[wid];
    aff[wid] = a;
    latA[wid] = a > 0.f ? a : 0.f;
  }
}

// ---------- K2: 9x9 reflect conv (wave per pixel) -> padded map interior ----------
__global__ void k_conv(const float* __restrict__ latA,
                       const float* __restrict__ sre,
                       float* __restrict__ latCp) {
  int wid = (blockIdx.x * blockDim.x + threadIdx.x) >> 6;
  int lane = threadIdx.x & 63;
  if (wid >= L) return;
  int i = wid >> 7, j = wid & (S - 1);
  float acc = 0.f;
#pragma unroll
  for (int t0 = 0; t0 < 2; ++t0) {
    int t = t0 * 64 + lane;
    if (t < EX * EX) {
      int u = t / EX, v = t - u * EX;
      int ii = reflect_idx(i + u - EX / 2);
      int jj = reflect_idx(j + v - EX / 2);
      acc += latA[ii * S + jj] * sre[t];
    }
  }
#pragma unroll
  for (int o = 32; o; o >>= 1) acc += __shfl_xor(acc, o);
  if (lane == 0) latCp[(i + 20) * PSTR + (j + 20)] = acc;
}

// ---------- K3: branchless partial sums over active k ----------
// grid = 512: blockIdx&255 -> 64-pixel group, blockIdx>>8 -> k-half.
// part[half*L + l] = sum over assigned k of lwT_e[k][l] * mapp[pixel + offset(k)]
__global__ __launch_bounds__(1024)
void k_part(const float* __restrict__ lwT,
            const int2* __restrict__ klist,
            const int* __restrict__ nactp,
            const float* __restrict__ mapp,
            float* __restrict__ part) {
  int b = blockIdx.x & 255;
  int half = blockIdx.x >> 8;
  int tid = threadIdx.x;
  int wave = tid >> 6, lane = tid & 63;
  int l0 = b << 6;
  int i = l0 >> 7;
  int jb = (b & 1) << 6;
  int nact = *nactp;
  if (nact > KLMAX) nact = KLMAX;
  __shared__ int2 kl[KLMAX];
  for (int t = tid; t < nact; t += 1024) kl[t] = klist[t];
  __syncthreads();
  int mbase = (i + 20) * PSTR + (jb + 20) + lane;
  float acc = 0.f;
#pragma unroll 8
  for (int t = half * 16 + wave; t < nact; t += 32) {
    int2 e = kl[t];
    float w = lwT[e.x + l0 + lane];
    float pv = mapp[mbase + e.y];
    acc = fmaf(w, pv, acc);
  }
  __shared__ float red[16][64];
  red[wave][lane] = acc;
  __syncthreads();
  if (wave == 0) {
    float s = 0.f;
#pragma unroll
    for (int w = 0; w < 16; ++w) s += red[w][lane];
    part[half * L + l0 + lane] = s;
  }
}

// ---------- K4: finalize lat2 = relu(latC - latneg + aff) * STRENGTH ----------
__global__ void k_latfin(const float* __restrict__ part,
                         const float* __restrict__ wsum,
                         const float* __restrict__ latCp,
                         const float* __restrict__ aff,
                         float* __restrict__ lat2) {
  int l = blockIdx.x * 256 + threadIdx.x;
  if (l >= L) return;
  float s = part[l] + part[L + l];
  int i = l >> 7, j = l & (S - 1);
  float lc = latCp[(i + 20) * PSTR + (j + 20)];
  float v = lc - s / wsum[l] + aff[l];
  lat2[l] = (v > 0.f ? v : 0.f) * 1.5f;
}

// ---------- K5: 19x19 masked max + normalize + mean accum ----------
__global__ void k_maxnorm(const float* __restrict__ lat2,
                          const float* __restrict__ mmask,
                          float* __restrict__ latA,
                          float* __restrict__ meanp,
                          float* __restrict__ out_lat,
                          int last) {
  int wid = (blockIdx.x * blockDim.x + threadIdx.x) >> 6;
  int lane = threadIdx.x & 63;
  if (wid >= L) return;
  int i = wid >> 7, j = wid & (S - 1);
  float m = 1.0f;
#pragma unroll
  for (int t0 = 0; t0 < 6; ++t0) {
    int t = t0 * 64 + lane;
    if (t < MAXR * MAXR) {
      int u = t / MAXR, v = t - u * MAXR;
      int ii = reflect_idx(i + u - MAXR / 2);
      int jj = reflect_idx(j + v - MAXR / 2);
      m = fmaxf(m, lat2[ii * S + jj] * mmask[t]);
    }
  }
#pragma unroll
  for (int o = 32; o; o >>= 1) m = fmaxf(m, __shfl_xor(m, o));
  if (lane == 0) {
    float lv = lat2[wid] / (m + 1e-5f);
    latA[wid] = lv;
    meanp[(i + 20) * PSTR + (j + 20)] += lv;
    if (last) out_lat[wid] = lv;
  }
}

// ---------- K6: correlation finalize ----------
__global__ void k_corrfin(const float* __restrict__ part,
                          const float* __restrict__ wsum,
                          const float* __restrict__ meanp,
                          float* __restrict__ out_cor) {
  int l = blockIdx.x * 256 + threadIdx.x;
  int tid = threadIdx.x;
  float c = 0.f;
  if (l < L) {
    const float inv_it = 1.0f / (float)NITER;
    float s = (part[l] + part[L + l]) * inv_it;
    int i = l >> 7, j = l & (S - 1);
    float lm = meanp[(i + 20) * PSTR + (j + 20)] * inv_it;
    c = lm * ((float)KK / wsum[l]) * s;
  }
#pragma unroll
  for (int o = 32; o; o >>= 1) c += __shfl_down(c, o);
  __shared__ float sm[4];
  if ((tid & 63) == 0) sm[tid >> 6] = c;
  __syncthreads();
  if (tid == 0) atomicAdd(out_cor, sm[0] + sm[1] + sm[2] + sm[3]);
}

// ================= fallback path (round-2 kernels, no transpose) =================

__device__ __forceinline__ float gmap(const float* __restrict__ m,
                                      int i, int j, int kh, int kw) {
  int ii = i + kh - LK / 2;
  int jj = j + kw - LK / 2;
  return ((unsigned)ii < (unsigned)S && (unsigned)jj < (unsigned)S)
             ? m[ii * S + jj] : 0.f;
}

__device__ __forceinline__ void row_scan(const float* __restrict__ lw,
                                         const float* __restrict__ envk,
                                         const float* __restrict__ m,
                                         int wid, int lane,
                                         float& accn, float& accw) {
  int i = wid >> 7, j = wid & (S - 1);
  const float* wrow = lw + (size_t)wid * KK;
  const int pro = (4 - (wid & 3)) & 3;
  const int n4 = (KK - pro) >> 2;
  const int tail = (KK - pro) & 3;
  accn = 0.f; accw = 0.f;
  if (lane < pro) {
    int k = lane;
    float w = wrow[k];
    int kh = k / LK, kw = k - kh * LK;
    accw += w;
    accn += w * envk[k] * gmap(m, i, j, kh, kw);
  }
  const float4* wrow4 = (const float4*)(wrow + pro);
  for (int q = lane; q < n4; q += 64) {
    float4 w4 = wrow4[q];
    int k0 = pro + (q << 2);
    int kh = k0 / LK;
    int kw = k0 - kh * LK;
    accw += (w4.x + w4.y) + (w4.z + w4.w);
    float a;
    a = w4.x * envk[k0]     * gmap(m, i, j, kh, kw);
    kw++; if (kw >= LK) { kw -= LK; kh++; }
    a += w4.y * envk[k0 + 1] * gmap(m, i, j, kh, kw);
    kw++; if (kw >= LK) { kw -= LK; kh++; }
    a += w4.z * envk[k0 + 2] * gmap(m, i, j, kh, kw);
    kw++; if (kw >= LK) { kw -= LK; kh++; }
    a += w4.w * envk[k0 + 3] * gmap(m, i, j, kh, kw);
    accn += a;
  }
  if (lane < tail) {
    int k = pro + (n4 << 2) + lane;
    float w = wrow[k];
    int kh = k / LK, kw = k - kh * LK;
    accw += w;
    accn += w * envk[k] * gmap(m, i, j, kh, kw);
  }
  wave_red2(accn, accw);
}

__global__ void k_latneg_fb(const float* __restrict__ lw,
                            const float* __restrict__ envk,
                            const float* __restrict__ latC,
                            const float* __restrict__ aff,
                            float* __restrict__ lat2) {
  int wid = (blockIdx.x * blockDim.x + threadIdx.x) >> 6;
  int lane = threadIdx.x & 63;
  if (wid >= L) return;
  float accn, accw;
  row_scan(lw, envk, latC, wid, lane, accn, accw);
  if (lane == 0) {
    float ln = accn / accw;
    float v = latC[wid] - ln + aff[wid];
    lat2[wid] = (v > 0.f ? v : 0.f) * 1.5f;
  }
}

__global__ void k_conv_fb(const float* __restrict__ latA,
                          const float* __restrict__ sre,
                          float* __restrict__ latC) {
  int wid = (blockIdx.x * blockDim.x + threadIdx.x) >> 6;
  int lane = threadIdx.x & 63;
  if (wid >= L) return;
  int i = wid >> 7, j = wid & (S - 1);
  float acc = 0.f;
#pragma unroll
  for (int t0 = 0; t0 < 2; ++t0) {
    int t = t0 * 64 + lane;
    if (t < EX * EX) {
      int u = t / EX, v = t - u * EX;
      int ii = reflect_idx(i + u - EX / 2);
      int jj = reflect_idx(j + v - EX / 2);
      acc += latA[ii * S + jj] * sre[t];
    }
  }
#pragma unroll
  for (int o = 32; o; o >>= 1) acc += __shfl_xor(acc, o);
  if (lane == 0) latC[wid] = acc;
}

__global__ void k_maxnorm_fb(const float* __restrict__ lat2,
                             const float* __restrict__ mmask,
                             float* __restrict__ latA,
                             float* __restrict__ mean,
                             float* __restrict__ out_lat,
                             int last) {
  int wid = (blockIdx.x * blockDim.x + threadIdx.x) >> 6;
  int lane = threadIdx.x & 63;
  if (wid >= L) return;
  int i = wid >> 7, j = wid & (S - 1);
  float m = 1.0f;
#pragma unroll
  for (int t0 = 0; t0 < 6; ++t0) {
    int t = t0 * 64 + lane;
    if (t < MAXR * MAXR) {
      int u = t / MAXR, v = t - u * MAXR;
      int ii = reflect_idx(i + u - MAXR / 2);
      int jj = reflect_idx(j + v - MAXR / 2);
      m = fmaxf(m, lat2[ii * S + jj] * mmask[t]);
    }
  }
#pragma unroll
  for (int o = 32; o; o >>= 1) m = fmaxf(m, __shfl_xor(m, o));
  if (lane == 0) {
    float lv = lat2[wid] / (m + 1e-5f);
    latA[wid] = lv;
    mean[wid] += lv;
    if (last) out_lat[wid] = lv;
  }
}

__global__ void k_xtiles_fb(const float* __restrict__ x,
                            const float* __restrict__ rfs,
                            const float* __restrict__ adath,
                            const float* __restrict__ aenv,
                            float* __restrict__ out_raw,
                            float* __restrict__ out_xt,
                            float* __restrict__ aff,
                            float* __restrict__ latA,
                            float* __restrict__ mean) {
  int wid = (blockIdx.x * blockDim.x + threadIdx.x) >> 6;
  int lane = threadIdx.x & 63;
  if (wid >= L) return;
  int i = wid >> 7, j = wid & (S - 1);
  const float2* rrow2 = (const float2*)(rfs + (size_t)wid * PP);
  float2* xrow2 = (float2*)(out_xt + (size_t)wid * PP);
  const float2* aenv2 = (const float2*)aenv;
  float accd = 0.f, accs = 0.f;
  for (int q = lane; q < PP / 2; q += 64) {
    float2 w2 = rrow2[q];
    float2 e2 = aenv2[q];
    int p0 = q << 1;
    int c = (p0 >= 441) ? 1 : 0;
    int r = p0 - c * 441;
    int kh = r / AK, kw = r - kh * AK;
    float xt0 = x[c * (HX * HX) + (i + kh) * HX + (j + kw)] * e2.x;
    int p1 = p0 + 1;
    int c1 = (p1 >= 441) ? 1 : 0;
    int r1 = p1 - c1 * 441;
    int kh1 = r1 / AK, kw1 = r1 - kh1 * AK;
    float xt1 = x[c1 * (HX * HX) + (i + kh1) * HX + (j + kw1)] * e2.y;
    xrow2[q] = make_float2(xt0, xt1);
    accd += xt0 * w2.x + xt1 * w2.y;
    accs += w2.x + w2.y;
  }
  wave_red2(accd, accs);
  if (lane == 0) {
    out_raw[wid] = accd * ((float)PP / accs);
    float a = accd / accs - adath[wid];
    aff[wid] = a;
    latA[wid] = a > 0.f ? a : 0.f;
    mean[wid] = 0.f;
  }
}

__global__ void k_corrpart_fb(const float* __restrict__ lw,
                              const float* __restrict__ envk,
                              const float* __restrict__ mean,
                              float* __restrict__ part) {
  int wid = (blockIdx.x * blockDim.x + threadIdx.x) >> 6;
  int lane = threadIdx.x & 63;
  if (wid >= L) return;
  float accn, accw;
  row_scan(lw, envk, mean, wid, lane, accn, accw);
  if (lane == 0) {
    const float inv_it = 1.0f / (float)NITER;
    float lm = mean[wid] * inv_it;
    part[wid] = lm * ((float)KK / accw) * (accn * inv_it);
  }
}

__global__ void k_reduce_fb(const float* __restrict__ part,
                            float* __restrict__ out) {
  float a = 0.f;
  for (int idx = threadIdx.x; idx < L; idx += 256) a += part[idx];
#pragma unroll
  for (int o = 32; o; o >>= 1) a += __shfl_down(a, o);
  __shared__ float sm[4];
  if ((threadIdx.x & 63) == 0) sm[threadIdx.x >> 6] = a;
  __syncthreads();
  if (threadIdx.x == 0) out[0] = sm[0] + sm[1] + sm[2] + sm[3];
}

// ---------- launch ----------
extern "C" void kernel_launch(void* const* d_in, const int* in_sizes, int n_in,
                              void* d_out, int out_size, void* d_ws, size_t ws_size,
                              hipStream_t stream) {
  const float* x     = (const float*)d_in[0];
  const float* rfs   = (const float*)d_in[1];
  const float* lw    = (const float*)d_in[2];
  const float* adath = (const float*)d_in[3];
  const float* aenv  = (const float*)d_in[4];
  const float* sre   = (const float*)d_in[5];
  const float* envk  = (const float*)d_in[6];
  const float* mmask = (const float*)d_in[7];

  float* out = (float*)d_out;
  float* out_raw = out;             // 16384
  float* out_lat = out + L;         // 16384
  float* out_cor = out + 2 * L;     // 1
  float* out_xt  = out + 2 * L + 1; // 16384*882

  dim3 blk(256);
  dim3 grid_wave(L / 4);

  size_t need = ((size_t)KK * L + 2 * (size_t)MAPSZ + 8 * (size_t)L + 4 * KLMAX + 64)
                * sizeof(float);

  if (ws_size >= need) {
    float* wsf   = (float*)d_ws;
    float* lwT   = wsf;                          // KK*L
    float* latCp = wsf + (size_t)KK * L;         // MAPSZ
    float* meanp = latCp + MAPSZ;                // MAPSZ
    float* wsum  = meanp + MAPSZ;                // L
    float* aff   = wsum + L;
    float* latA  = aff + L;
    float* lat2  = latA + L;
    float* part  = lat2 + L;                     // 2*L
    int2*  klist = (int2*)(part + 2 * L);        // KLMAX int2
    int*   nact  = (int*)(klist + KLMAX);

    hipMemsetAsync(latCp, 0, 2 * MAPSZ * sizeof(float), stream);  // latCp + meanp
    hipMemsetAsync(wsum, 0, L * sizeof(float), stream);
    hipMemsetAsync(out_cor, 0, sizeof(float), stream);

    k_klist<<<1, 64, 0, stream>>>(envk, klist, nact);
    k_transpose<<<dim3(27, 256), blk, 0, stream>>>(lw, envk, lwT, wsum);
    k_xtiles<<<grid_wave, blk, 0, stream>>>(x, rfs, adath, aenv,
                                            out_raw, out_xt, aff, latA);
    for (int it = 0; it < NITER; ++it) {
      k_conv<<<grid_wave, blk, 0, stream>>>(latA, sre, latCp);
      k_part<<<dim3(512), dim3(1024), 0, stream>>>(lwT, klist, nact, latCp, part);
      k_latfin<<<dim3(64), blk, 0, stream>>>(part, wsum, latCp, aff, lat2);
      k_maxnorm<<<grid_wave, blk, 0, stream>>>(lat2, mmask, latA, meanp, out_lat,
                                               (it == NITER - 1) ? 1 : 0);
    }
    k_part<<<dim3(512), dim3(1024), 0, stream>>>(lwT, klist, nact, meanp, part);
    k_corrfin<<<dim3(64), blk, 0, stream>>>(part, wsum, meanp, out_cor);
  } else {
    float* wsf  = (float*)d_ws;
    float* aff  = wsf;
    float* latA = wsf + L;
    float* latC = wsf + 2 * L;
    float* lat2 = wsf + 3 * L;
    float* mean = wsf + 4 * L;
    float* part = wsf + 5 * L;

    k_xtiles_fb<<<grid_wave, blk, 0, stream>>>(x, rfs, adath, aenv,
                                               out_raw, out_xt, aff, latA, mean);
    for (int it = 0; it < NITER; ++it) {
      k_conv_fb<<<grid_wave, blk, 0, stream>>>(latA, sre, latC);
      k_latneg_fb<<<grid_wave, blk, 0, stream>>>(lw, envk, latC, aff, lat2);
      k_maxnorm_fb<<<grid_wave, blk, 0, stream>>>(lat2, mmask, latA, mean, out_lat,
                                                  (it == NITER - 1) ? 1 : 0);
    }
    k_corrpart_fb<<<grid_wave, blk, 0, stream>>>(lw, envk, mean, part);
    k_reduce_fb<<<1, blk, 0, stream>>>(part, out_cor);
  }
}